// Round 7
// baseline (1886.660 us; speedup 1.0000x reference)
//
#include <hip/hip_runtime.h>
#include <cstdint>
#include <cstddef>

// Problem dims (fixed by reference)
#define B_   128
#define T_   32
#define IN_  2048
#define H_   2048
#define OUT_ 512

// address-space helper types for global_load_lds
typedef __attribute__((address_space(1))) const void* gas_cp;
typedef __attribute__((address_space(3))) void* las_p;

// ---------- kernel 1: transpose spikes ----------
__global__ __launch_bounds__(256) void k_transpose(const float* __restrict__ in,
                                                   float* __restrict__ Xt) {
    int idx = blockIdx.x * 256 + threadIdx.x;   // b*IN + i
    int b = idx >> 11;
    int i = idx & (IN_ - 1);
    const float4* p = (const float4*)(in + (size_t)idx * T_);
#pragma unroll
    for (int q = 0; q < 8; ++q) {
        float4 v = p[q];
        int t = q * 4;
        Xt[((size_t)((t + 0) * B_ + b) << 11) + i] = v.x;
        Xt[((size_t)((t + 1) * B_ + b) << 11) + i] = v.y;
        Xt[((size_t)((t + 2) * B_ + b) << 11) + i] = v.z;
        Xt[((size_t)((t + 3) * B_ + b) << 11) + i] = v.w;
    }
}

// ---------- kernel 2a: fp32 GEMM 128x128, BK=16, 8x8/thread, C-RMW,
//            cross-granule fragment double-buffer --------------------------
// Exact-chain semantics preserved (verified through round 6):
//   C = ((chain(0..511) + chain(512..1023)) + chain(1024..1535)) + chain(1536..2047)
// per C element: ascending-k fp32 FMA chain within each KC=512 block (tile asc,
// granule asc, q asc), KC blocks joined in GLOBAL memory by the owning thread
// (volatile RMW: C=c1; C+=c2; C+=c3; C+=c4 — ascending, bit-exact BLIS join).
// ROUND-7: occupancy is GRID-capped at 2 waves/SIMD (512 blocks = 2/CU x 4
// waves), so registers up to 256 are free. Use them for what round 4 couldn't:
// double-buffer the per-granule fragments (wvA/avA vs wvB/avB, 128 frag regs +
// acc 64 ~ 220 total) so granule g+1's 16 ds_read_b128 are in flight during
// g's 256 FMAs -> in-wave LDS latency hidden. waves_per_eu(1,2) = the one
// proven-benign budget setting (round 3: 192 regs, no spill; round-5 (4,4)
// and bare launch_bounds both spilled). Tripwires: WRITE_SIZE >> 131 MB or
// FETCH >> 243 MB = spill -> revert.
// Pair-row XOR swizzle (round 6, measured ZERO bank conflicts): granule
// (row r, s) at group u=r>>1, slot ((s<<1)|(r&1)) ^ (u&7); read address =
// base ^ (gk<<5) ^ bufbit, all literals via pair-unrolled kt loop.
__global__ __launch_bounds__(256)
__attribute__((amdgpu_waves_per_eu(1, 2)))
void k_gemm_128(const float* __restrict__ A, const float* __restrict__ W,
                float* __restrict__ C, int M, int N, int K) {
    constexpr int BK = 16;
    constexpr int BUFF = 4096;                  // floats per buffer (16 KB)
    __shared__ alignas(16) float lds[2][BUFF];  // 32 KB double-buffered

    const int tid = threadIdx.x;
    const int tx  = tid & 15;        // n direction
    const int ty  = tid >> 4;        // m direction
    const int m0  = blockIdx.y * 128;
    const int n0  = blockIdx.x * 128;
    const int w   = tid >> 6;        // wave id 0..3

    // ---- staging: per tile 512 granules per operand -> 2 glds/thread each.
    // LDS linear slot L=(u,c) receives source (row 2u+h, granule s) where
    // v = c ^ (u&7), h = v&1, s = v>>1.
    const float* srcA[2];
    const float* srcW[2];
    int dstA[2], dstW[2];
#pragma unroll
    for (int q = 0; q < 2; ++q) {
        int L = q * 256 + tid;                 // 0..511
        int u = L >> 3, c = L & 7;
        int v = c ^ (u & 7);
        int r = 2 * u + (v & 1);               // source row 0..127
        int s = v >> 1;                        // source granule 0..3
        srcA[q] = A + (size_t)(m0 + r) * K + s * 4;
        srcW[q] = W + (size_t)(n0 + r) * K + s * 4;
        dstA[q] = q * 1024 + w * 256;          // float offset (wave-uniform)
        dstW[q] = 2048 + q * 1024 + w * 256;   // W region starts at 8 KB
    }

    // ---- fragment read byte-offsets; granule gk of row r lives at
    // u*128 + (((r&1)^(u&1))<<4) + ((((u>>1)&3) ^ gk)<<5); read = base ^ (gk<<5).
    int offA[8], offW[8];
#pragma unroll
    for (int i = 0; i < 8; ++i) {
        int r = ty + 16 * i;
        int u = r >> 1, y = u & 7;
        offA[i] = u * 128 + (((r & 1) ^ (y & 1)) << 4) + ((y >> 1) << 5);
        r = tx + 16 * i;
        u = r >> 1; y = u & 7;
        offW[i] = 8192 + u * 128 + (((r & 1) ^ (y & 1)) << 4) + ((y >> 1) << 5);
    }

    float acc[8][8];                 // in-KC-block FMA chain
#pragma unroll
    for (int i = 0; i < 8; ++i)
#pragma unroll
        for (int j = 0; j < 8; ++j) acc[i][j] = 0.0f;

    const char* lbase = (const char*)&lds[0][0];
    const size_t cb = (size_t)(m0 + ty) * N + (n0 + tx);

    float4 wvA[8], wvB[8], avA[8], avB[8];   // double-buffered fragments

#define STAGE(NB)                                                           \
    {                                                                       \
        _Pragma("unroll")                                                   \
        for (int q = 0; q < 2; ++q) {                                       \
            __builtin_amdgcn_global_load_lds((gas_cp)srcA[q],               \
                (las_p)&lds[NB][dstA[q]], 16, 0, 0);                        \
            __builtin_amdgcn_global_load_lds((gas_cp)srcW[q],               \
                (las_p)&lds[NB][dstW[q]], 16, 0, 0);                        \
            srcA[q] += BK;                                                  \
            srcW[q] += BK;                                                  \
        }                                                                   \
    }

#define LOADG(GKL, WV, AV)                                                  \
    {                                                                       \
        _Pragma("unroll")                                                   \
        for (int j = 0; j < 8; ++j)                                         \
            WV[j] = *(const float4*)(lbase + (offW[j] ^ (GKL)));            \
        _Pragma("unroll")                                                   \
        for (int i = 0; i < 8; ++i)                                         \
            AV[i] = *(const float4*)(lbase + (offA[i] ^ (GKL)));            \
    }

// q ascends within a granule; granules issued ascending -> exact chain.
#define FMAG(WV, AV)                                                        \
    {                                                                       \
        _Pragma("unroll")                                                   \
        for (int q = 0; q < 4; ++q)                                         \
            _Pragma("unroll")                                               \
            for (int i = 0; i < 8; ++i)                                     \
                _Pragma("unroll")                                           \
                for (int j = 0; j < 8; ++j)                                 \
                    acc[i][j] = __builtin_fmaf(((const float*)&AV[i])[q],   \
                                               ((const float*)&WV[j])[q],   \
                                               acc[i][j]);                  \
    }

// One BK=16 tile in buffer byte-offset BB (0 or 16384), optionally staging
// the next tile into buffer NB. Granule pipeline: reads run one granule
// ahead of the FMA blocks.
#define TILE(BB, NB, DO_PF)                                                 \
    {                                                                       \
        __syncthreads();                                                    \
        LOADG((BB) | 0, wvA, avA)                                           \
        if (DO_PF) STAGE(NB)                                                \
        LOADG((BB) | 32, wvB, avB)                                          \
        FMAG(wvA, avA)                                                      \
        LOADG((BB) | 64, wvA, avA)                                          \
        FMAG(wvB, avB)                                                      \
        LOADG((BB) | 96, wvB, avB)                                          \
        FMAG(wvA, avA)                                                      \
        FMAG(wvB, avB)                                                      \
    }

    // prologue: stage tile 0 into buffer 0
    STAGE(0)

    for (int kt = 0; kt < 128; kt += 2) {    // K = 2048: 128 BK-tiles, paired
        TILE(0, 1, 1)                        // even tile in buf0; stage -> buf1
        TILE(16384, 0, (kt < 126))           // odd tile in buf1; stage -> buf0

        // KC=512 boundary (after tiles 31/63/95/127): fold chain into C in
        // global memory, same thread, ascending KC order -> exact BLIS join.
        // volatile forbids register-forwarding C across boundaries.
        if (((kt + 2) & 31) == 0) {
            volatile float* Cv = (volatile float*)C;
            if (kt == 30) {
#pragma unroll
                for (int i = 0; i < 8; ++i) {
                    size_t rowb = cb + (size_t)(i * 16) * N;
#pragma unroll
                    for (int j = 0; j < 8; ++j) {
                        Cv[rowb + j * 16] = acc[i][j];   // tot = 0 + c1 exact
                        acc[i][j] = 0.0f;
                    }
                }
            } else {
#pragma unroll
                for (int i = 0; i < 8; ++i) {
                    size_t rowb = cb + (size_t)(i * 16) * N;
#pragma unroll
                    for (int j = 0; j < 8; ++j) {
                        float t = Cv[rowb + j * 16];
                        Cv[rowb + j * 16] = t + acc[i][j];  // tot + c_b
                        acc[i][j] = 0.0f;
                    }
                }
            }
        }
    }

#undef TILE
#undef FMAG
#undef LOADG
#undef STAGE
}

// ---------- kernel 2b: fp32 GEMM 64x128 tile, 4x8/thread (output layer) ------
// Round-1 kernel verbatim (proven). N=512: grid (4,64) = 256 blocks = 1/CU.
__global__ __launch_bounds__(256)
void k_gemm_seq(const float* __restrict__ A, const float* __restrict__ W,
                float* __restrict__ C, int M, int N, int K) {
    constexpr int BM = 64, BN = 128, BK = 32;
    constexpr int NT = 8;                       // n per thread (BN/16)
    constexpr int BUFF = (BM + BN) * BK;        // 6144 floats = 24 KB
    __shared__ alignas(16) float lds[2][BUFF];  // 48 KB double-buffered

    const int tid = threadIdx.x;
    const int tx  = tid & 15;        // n direction
    const int ty  = tid >> 4;        // m direction
    const int m0  = blockIdx.y * BM;
    const int n0  = blockIdx.x * BN;
    const int w   = tid >> 6;        // wave id 0..3

    const float* srcA[2];
    int dstA[2];
#pragma unroll
    for (int q = 0; q < 2; ++q) {
        int L = q * 256 + tid;
        int r = L >> 3;
        int s = ((L & 7) - ((r + (r >> 4)) & 7)) & 7;
        srcA[q] = A + (size_t)(m0 + r) * K + s * 4;
        dstA[q] = q * 1024 + w * 256;
    }
    const float* srcW[4];
    int dstW[4];
#pragma unroll
    for (int q = 0; q < 4; ++q) {
        int L = q * 256 + tid;
        int r = L >> 3;
        int s = ((L & 7) - ((r + (r >> 4)) & 7)) & 7;
        srcW[q] = W + (size_t)(n0 + r) * K + s * 4;
        dstW[q] = BM * BK + q * 1024 + w * 256;
    }

    float acc[4][NT];
    float tot[4][NT];
#pragma unroll
    for (int i = 0; i < 4; ++i)
#pragma unroll
        for (int j = 0; j < NT; ++j) { acc[i][j] = 0.0f; tot[i][j] = 0.0f; }

    const int nkt = K / BK;

#pragma unroll
    for (int q = 0; q < 2; ++q) {
        __builtin_amdgcn_global_load_lds((gas_cp)srcA[q], (las_p)&lds[0][dstA[q]], 16, 0, 0);
        srcA[q] += BK;
    }
#pragma unroll
    for (int q = 0; q < 4; ++q) {
        __builtin_amdgcn_global_load_lds((gas_cp)srcW[q], (las_p)&lds[0][dstW[q]], 16, 0, 0);
        srcW[q] += BK;
    }

    int cur = 0;
    for (int kt = 0; kt < nkt; ++kt) {
        __syncthreads();

        if (kt + 1 < nkt) {
            int nb = cur ^ 1;
#pragma unroll
            for (int q = 0; q < 2; ++q) {
                __builtin_amdgcn_global_load_lds((gas_cp)srcA[q], (las_p)&lds[nb][dstA[q]], 16, 0, 0);
                srcA[q] += BK;
            }
#pragma unroll
            for (int q = 0; q < 4; ++q) {
                __builtin_amdgcn_global_load_lds((gas_cp)srcW[q], (las_p)&lds[nb][dstW[q]], 16, 0, 0);
                srcW[q] += BK;
            }
        }

        const float* At = &lds[cur][0];
        const float* Wt = &lds[cur][BM * BK];

#pragma unroll
        for (int gk = 0; gk < 8; ++gk) {
            float4 av[4], wv[NT];
#pragma unroll
            for (int i = 0; i < 4; ++i) {
                int r = ty + 16 * i;
                int rot = (r + (r >> 4)) & 7;
                av[i] = *(const float4*)&At[r * BK + (((gk + rot) & 7) << 2)];
            }
#pragma unroll
            for (int j = 0; j < NT; ++j) {
                int r = tx + 16 * j;
                int rot = (r + (r >> 4)) & 7;
                wv[j] = *(const float4*)&Wt[r * BK + (((gk + rot) & 7) << 2)];
            }
#pragma unroll
            for (int q = 0; q < 4; ++q)
#pragma unroll
                for (int i = 0; i < 4; ++i)
#pragma unroll
                    for (int j = 0; j < NT; ++j)
                        acc[i][j] = __builtin_fmaf(((const float*)&av[i])[q],
                                                   ((const float*)&wv[j])[q],
                                                   acc[i][j]);
        }

        if (((kt + 1) & 15) == 0) {
#pragma unroll
            for (int i = 0; i < 4; ++i)
#pragma unroll
                for (int j = 0; j < NT; ++j) {
                    tot[i][j] = tot[i][j] + acc[i][j];
                    acc[i][j] = 0.0f;
                }
        }
        cur ^= 1;
    }

#pragma unroll
    for (int i = 0; i < 4; ++i)
#pragma unroll
        for (int j = 0; j < NT; ++j)
            C[(size_t)(m0 + ty + 16 * i) * N + (n0 + tx + 16 * j)] = tot[i][j];
}

// ---------- kernel 3: LIF scan over t for hidden layers (fp32, numpy order) --
__global__ __launch_bounds__(256) void k_scan_h(const float* __restrict__ Acc,
                                                const float* __restrict__ v_init,
                                                const float* __restrict__ s_init,
                                                const float* __restrict__ bias,
                                                float* __restrict__ Sout) {
    int idx = blockIdx.x * 256 + threadIdx.x;  // b*H + h
    int h = idx & (H_ - 1);
    float v = v_init[idx];
    float s = s_init[idx];
    float bb = bias[h];
#pragma unroll
    for (int t = 0; t < T_; ++t) {
        float x = Acc[(size_t)t * (B_ * H_) + idx];
        float d = 0.5f * v;          // exact (power of two)
        d = d * (1.0f - s);          // exact (x{0,1})
        v = d + x;
        v = v + bb;
        s = (v > 0.5f) ? 1.0f : 0.0f;
        Sout[(size_t)t * (B_ * H_) + idx] = s;
    }
}

// ---------- kernel 4: LIF scan + spike count for output layer ----------
__global__ __launch_bounds__(256) void k_scan_o(const float* __restrict__ Acc,
                                                const float* __restrict__ v_init,
                                                const float* __restrict__ s_init,
                                                const float* __restrict__ bias,
                                                float* __restrict__ out) {
    int idx = blockIdx.x * 256 + threadIdx.x;  // b*OUT + o
    int o = idx & (OUT_ - 1);
    float v = v_init[idx];
    float s = s_init[idx];
    float bb = bias[o];
    float acc = 0.0f;
#pragma unroll
    for (int t = 0; t < T_; ++t) {
        float x = Acc[(size_t)t * (B_ * OUT_) + idx];
        float d = 0.5f * v;
        d = d * (1.0f - s);
        v = d + x;
        v = v + bb;
        s = (v > 0.5f) ? 1.0f : 0.0f;
        acc += s;                    // integer-valued, exact in fp32
    }
    out[idx] = acc;
}

// ---------- launch ----------

extern "C" void kernel_launch(void* const* d_in, const int* in_sizes, int n_in,
                              void* d_out, int out_size, void* d_ws, size_t ws_size,
                              hipStream_t stream) {
    const float* spike_data = (const float*)d_in[0];
    const float* h0_volt  = (const float*)d_in[1];
    const float* h0_spike = (const float*)d_in[2];
    const float* h1_volt  = (const float*)d_in[3];
    const float* h1_spike = (const float*)d_in[4];
    const float* o_volt   = (const float*)d_in[5];
    const float* o_spike  = (const float*)d_in[6];
    const float* W0 = (const float*)d_in[7];
    const float* b0 = (const float*)d_in[8];
    const float* W1 = (const float*)d_in[9];
    const float* b1 = (const float*)d_in[10];
    const float* Wo = (const float*)d_in[11];
    const float* bo = (const float*)d_in[12];
    float* out = (float*)d_out;

    // workspace layout (96 MB)
    char* ws = (char*)d_ws;
    const size_t MB = (size_t)1 << 20;
    float* Xt = (float*)(ws);             // 32 MB [T*B][IN]; reused as S1
    float* S0 = (float*)(ws + 32 * MB);   // 32 MB [T*B][H]
    float* Ab = (float*)(ws + 64 * MB);   // 32 MB [T*B][H] (or [T*B][OUT])
    float* S1 = Xt;                       // Xt dead after GEMM0

    const int M = T_ * B_;   // 4096

    k_transpose<<<(B_ * IN_) / 256, 256, 0, stream>>>(spike_data, Xt);

    // layer 0: A0 = Xt @ W0^T   [4096,2048] x [2048,2048]  (K=2048 fixed)
    k_gemm_128<<<dim3(H_ / 128, M / 128), 256, 0, stream>>>(Xt, W0, Ab, M, H_, IN_);
    k_scan_h<<<(B_ * H_) / 256, 256, 0, stream>>>(Ab, h0_volt, h0_spike, b0, S0);

    // layer 1: A1 = S0 @ W1^T
    k_gemm_128<<<dim3(H_ / 128, M / 128), 256, 0, stream>>>(S0, W1, Ab, M, H_, H_);
    k_scan_h<<<(B_ * H_) / 256, 256, 0, stream>>>(Ab, h1_volt, h1_spike, b1, S1);

    // output: Ao = S1 @ Wo^T   [4096,2048] x [2048,512]
    k_gemm_seq<<<dim3(OUT_ / 128, M / 64), 256, 0, stream>>>(S1, Wo, Ab, M, OUT_, H_);
    k_scan_o<<<(B_ * OUT_) / 256, 256, 0, stream>>>(Ab, o_volt, o_spike, bo, out);

    (void)in_sizes; (void)n_in; (void)out_size; (void)ws_size;
}